// Round 1
// baseline (24164.064 us; speedup 1.0000x reference)
//
#include <hip/hip_runtime.h>

typedef __attribute__((ext_vector_type(8))) short short8;
typedef __attribute__((ext_vector_type(4))) float floatx4;

#define B_   128
#define T_   1024
#define D_   256
#define HS_  512
#define NKT  24            // K = 768 = 24 * 32

// workspace layout (bytes)
#define OFF_X   0ull
#define SZ_X    ((size_t)B_*T_*D_*2)            // 64 MiB  x in bf16
#define OFF_W   (OFF_X + SZ_X)
#define SZ_W    ((size_t)16*4*48*64*8*2)        // 3 MiB   weight fragments
#define OFF_H   (OFF_W + SZ_W)
#define SZ_H    ((size_t)2*B_*HS_*2)            // 256 KiB h double buffer (bf16)
#define OFF_C   (OFF_H + SZ_H)                  // counters, 256B stride per group

__device__ inline unsigned short f2bf(float f){
  union { float f; unsigned u; } v; v.f = f;
  unsigned r = v.u + 0x7FFFu + ((v.u >> 16) & 1u);
  return (unsigned short)(r >> 16);
}

// ---- zero h buffer + barrier counters (ws is poisoned 0xAA every call) ----
__global__ void k_zero(unsigned* __restrict__ hbuf32, unsigned* __restrict__ cnt32){
  int i = blockIdx.x*256 + threadIdx.x;
  if (i < (int)(SZ_H/4)) hbuf32[i] = 0u;
  if (i < 512)           cnt32[i]  = 0u;
}

// ---- convert x fp32 -> bf16 ----
__global__ void k_convx(const float* __restrict__ x, unsigned short* __restrict__ xb){
  size_t i = ((size_t)blockIdx.x*256 + threadIdx.x)*8;
  const float* s = x + i;
  short8 r;
#pragma unroll
  for (int j=0;j<8;j++) r[j] = (short)f2bf(s[j]);
  *(short8*)(void*)(xb + i) = r;
}

// ---- pre-swizzle [W;U] into MFMA B-fragment order, bf16 ----
// layout: flat = (((sub*4 + w)*24 + kt)*2 + nt)*64 + lane, 8 bf16 per flat entry
// value[j] = K<256 ? W[K][col] : U[K-256][col]
//   K   = kt*32 + (lane>>4)*8 + j
//   col = w*512 + sub*32 + nt*16 + (lane&15)
__global__ void k_wfrag(const float* __restrict__ W, const float* __restrict__ U,
                        unsigned short* __restrict__ wf){
  int flat = blockIdx.x*256 + threadIdx.x;       // 0..196607
  int lane = flat & 63;
  int rest = flat >> 6;                          // 0..3071
  int nt   = rest & 1;
  int kt   = (rest >> 1) % 24;
  int sw   = (rest >> 1) / 24;                   // sub*4 + w
  int w    = sw & 3;
  int sub  = sw >> 2;
  int colg  = w*HS_ + sub*32 + nt*16 + (lane & 15);
  int kbase = kt*32 + (lane >> 4)*8;
  short8 r;
#pragma unroll
  for (int j=0;j<8;j++){
    int k = kbase + j;
    float v = (k < D_) ? W[(size_t)k*2048 + colg] : U[(size_t)(k-D_)*2048 + colg];
    r[j] = (short)f2bf(v);
  }
  *(short8*)(void*)(wf + (size_t)flat*8) = r;
}

// ---- persistent recurrence kernel ----
// grid = 128 WGs x 256 thr. group = wg>>4 owns batch rows [16g,16g+16);
// sub = wg&15 owns h cols [32*sub, 32*sub+32). wave w computes gate chunk w
// (i/f/g/o), 16x32 tile, K=768 via MFMA 16x16x32 bf16 with register-resident B.
__global__ __launch_bounds__(256, 1) void k_lstm(
  const unsigned short* __restrict__ xb,
  const unsigned short* __restrict__ wf,
  const float* __restrict__ bias,
  unsigned short* __restrict__ hbuf,
  unsigned int* __restrict__ cnt,
  float* __restrict__ out)
{
  __shared__ unsigned short A_lds[NKT*64*8];   // 24 KiB, fragment-order
  __shared__ float g_lds[4][16][34];           // gates, padded

  const int wg   = blockIdx.x;
  const int group = wg >> 4, sub = wg & 15;
  const int tid  = threadIdx.x;
  const int wave = tid >> 6, lane = tid & 63;

  // B fragments: 48 x (16B/lane) = 192 VGPRs, resident all 1024 steps
  short8 bw[48];
  {
    const unsigned short* wp = wf + (size_t)(sub*4 + wave)*48*512 + (size_t)lane*8;
#pragma unroll
    for (int i=0;i<48;i++) bw[i] = *(const short8*)(const void*)(wp + i*512);
  }

  // elementwise mapping: row_e = tid>>4, two h-cols per thread
  const int row_e = tid >> 4;
  const int cp    = (tid & 15)*2;
  float bres[8];
#pragma unroll
  for (int q=0;q<4;q++)
#pragma unroll
    for (int e=0;e<2;e++)
      bres[q*2+e] = bias[q*HS_ + sub*32 + cp + e];

  float c0 = 0.f, c1 = 0.f;
  unsigned int* mycnt = cnt + group*64;   // 256B stride
  const size_t HSQ = (size_t)B_*T_*HS_;
  const int grow = group*16 + row_e;
  const int gcol = sub*32 + cp;

  for (int t=0; t<T_; ++t){
    // ---- stage A = [x_t | h_{t}] into LDS in fragment order ----
    const unsigned short* hsrc = hbuf + (size_t)(t & 1)*B_*HS_;
#pragma unroll
    for (int it=0; it<6; ++it){
      int id  = tid + it*256;          // 0..1535
      int row = id & 15;
      int kc  = id >> 4;               // 0..95
      int k   = kc*8;
      const unsigned short* src;
      if (k < D_) src = xb + ((size_t)(group*16+row)*T_ + t)*D_ + k;
      else        src = hsrc + (size_t)(group*16+row)*HS_ + (k - D_);
      short8 v = *(const short8*)(const void*)src;
      int kt = k >> 5, quad = (k >> 3) & 3;
      int dl = (quad << 4) | row;
      *(short8*)(void*)&A_lds[(kt*64 + dl)*8] = v;
    }
    __syncthreads();

    // ---- MFMA: gates[16 x 32] for chunk `wave`, K=768 ----
    floatx4 acc0 = {0.f,0.f,0.f,0.f}, acc1 = {0.f,0.f,0.f,0.f};
#pragma unroll
    for (int kt=0; kt<NKT; ++kt){
      short8 a = *(const short8*)(const void*)&A_lds[(kt*64 + lane)*8];
      acc0 = __builtin_amdgcn_mfma_f32_16x16x32_bf16(a, bw[kt*2+0], acc0, 0,0,0);
      acc1 = __builtin_amdgcn_mfma_f32_16x16x32_bf16(a, bw[kt*2+1], acc1, 0,0,0);
    }
    // C/D layout: col = lane&15, row = (lane>>4)*4 + reg
#pragma unroll
    for (int r=0;r<4;r++){
      int row = (lane>>4)*4 + r;
      g_lds[wave][row][(lane&15)]    = acc0[r];
      g_lds[wave][row][16+(lane&15)] = acc1[r];
    }
    __syncthreads();

    // ---- LSTM cell, 2 h/c values per thread (c in registers) ----
    float hv0, hv1;
    {
      float gi = g_lds[0][row_e][cp]   + bres[0];
      float gf = g_lds[1][row_e][cp]   + bres[2];
      float gg = g_lds[2][row_e][cp]   + bres[4];
      float go = g_lds[3][row_e][cp]   + bres[6];
      float i_ = 1.f/(1.f + __expf(-gi));
      float f_ = 1.f/(1.f + __expf(-gf));
      float g_ = 1.f - 2.f/(__expf(2.f*gg)+1.f);
      float o_ = 1.f/(1.f + __expf(-go));
      c0 = f_*c0 + i_*g_;
      hv0 = o_*(1.f - 2.f/(__expf(2.f*c0)+1.f));
    }
    {
      float gi = g_lds[0][row_e][cp+1] + bres[1];
      float gf = g_lds[1][row_e][cp+1] + bres[3];
      float gg = g_lds[2][row_e][cp+1] + bres[5];
      float go = g_lds[3][row_e][cp+1] + bres[7];
      float i_ = 1.f/(1.f + __expf(-gi));
      float f_ = 1.f/(1.f + __expf(-gf));
      float g_ = 1.f - 2.f/(__expf(2.f*gg)+1.f);
      float o_ = 1.f/(1.f + __expf(-go));
      c1 = f_*c1 + i_*g_;
      hv1 = o_*(1.f - 2.f/(__expf(2.f*c1)+1.f));
    }

    // hidden_sequence (fp32)
    float2 h2; h2.x = hv0; h2.y = hv1;
    *(float2*)(out + ((size_t)grow*T_ + t)*HS_ + gcol) = h2;
    // next-step h (bf16, packed u32 store)
    unsigned short* hdst = hbuf + (size_t)((t+1)&1)*B_*HS_ + (size_t)grow*HS_ + gcol;
    *(unsigned int*)(void*)hdst = (unsigned)f2bf(hv0) | ((unsigned)f2bf(hv1) << 16);
    if (t == T_-1){
      *(float2*)(out + HSQ + (size_t)grow*HS_ + gcol) = h2;
      float2 cc; cc.x = c0; cc.y = c1;
      *(float2*)(out + HSQ + (size_t)B_*HS_ + (size_t)grow*HS_ + gcol) = cc;
    }

    // ---- per-group barrier (monotonic counter, agent scope) ----
    __threadfence();
    __syncthreads();
    if (tid == 0){
      __hip_atomic_fetch_add(mycnt, 1u, __ATOMIC_RELEASE, __HIP_MEMORY_SCOPE_AGENT);
      unsigned tgt = 16u*(unsigned)(t+1);
      while (__hip_atomic_load(mycnt, __ATOMIC_ACQUIRE, __HIP_MEMORY_SCOPE_AGENT) < tgt)
        __builtin_amdgcn_s_sleep(2);
    }
    __syncthreads();
    __threadfence();   // invalidate L1 before reading peers' h
  }
}

extern "C" void kernel_launch(void* const* d_in, const int* in_sizes, int n_in,
                              void* d_out, int out_size, void* d_ws, size_t ws_size,
                              hipStream_t stream){
  (void)in_sizes; (void)n_in; (void)out_size; (void)ws_size;
  const float* x    = (const float*)d_in[0];
  const float* W    = (const float*)d_in[1];
  const float* U    = (const float*)d_in[2];
  const float* bias = (const float*)d_in[3];
  char* ws = (char*)d_ws;
  unsigned short* xb = (unsigned short*)(ws + OFF_X);
  unsigned short* wf = (unsigned short*)(ws + OFF_W);
  unsigned short* hb = (unsigned short*)(ws + OFF_H);
  unsigned int*   cn = (unsigned int*)(ws + OFF_C);
  float* out = (float*)d_out;

  hipLaunchKernelGGL(k_zero,  dim3(256),   dim3(256), 0, stream, (unsigned*)hb, cn);
  hipLaunchKernelGGL(k_convx, dim3((B_*T_*D_/8)/256), dim3(256), 0, stream, x, xb);
  hipLaunchKernelGGL(k_wfrag, dim3(768),   dim3(256), 0, stream, W, U, wf);
  hipLaunchKernelGGL(k_lstm,  dim3(128),   dim3(256), 0, stream, xb, wf, bias, hb, cn, out);
}

// Round 2
// 4718.677 us; speedup vs baseline: 5.1209x; 5.1209x over previous
//
#include <hip/hip_runtime.h>

typedef __attribute__((ext_vector_type(8))) short short8;
typedef __attribute__((ext_vector_type(4))) float floatx4;

#define B_   128
#define T_   1024
#define D_   256
#define HS_  512
#define NKT  24            // K = 768 = 24 * 32

// workspace layout (bytes)
#define OFF_X   0ull
#define SZ_X    ((size_t)B_*T_*D_*2)            // 64 MiB  x in bf16
#define OFF_W   (OFF_X + SZ_X)
#define SZ_W    ((size_t)16*4*48*64*8*2)        // 3 MiB   weight fragments
#define OFF_H   (OFF_W + SZ_W)
#define SZ_H    ((size_t)2*B_*HS_*2)            // 256 KiB h double buffer (bf16)
#define OFF_C   (OFF_H + SZ_H)                  // counters, 256B stride per group

__device__ inline unsigned short f2bf(float f){
  union { float f; unsigned u; } v; v.f = f;
  unsigned r = v.u + 0x7FFFu + ((v.u >> 16) & 1u);
  return (unsigned short)(r >> 16);
}

// ---- zero h buffer + barrier counters (ws is poisoned 0xAA every call) ----
__global__ void k_zero(unsigned* __restrict__ hbuf32, unsigned* __restrict__ cnt32){
  int i = blockIdx.x*256 + threadIdx.x;
  if (i < (int)(SZ_H/4)) hbuf32[i] = 0u;
  if (i < 512)           cnt32[i]  = 0u;
}

// ---- convert x fp32 -> bf16 ----
__global__ void k_convx(const float* __restrict__ x, unsigned short* __restrict__ xb){
  size_t i = ((size_t)blockIdx.x*256 + threadIdx.x)*8;
  const float* s = x + i;
  short8 r;
#pragma unroll
  for (int j=0;j<8;j++) r[j] = (short)f2bf(s[j]);
  *(short8*)(void*)(xb + i) = r;
}

// ---- pre-swizzle [W;U] into MFMA B-fragment order, bf16 ----
// layout: flat = (((sub*4 + w)*24 + kt)*2 + nt)*64 + lane, 8 bf16 per flat entry
// value[j] = K<256 ? W[K][col] : U[K-256][col]
//   K   = kt*32 + (lane>>4)*8 + j
//   col = w*512 + sub*32 + nt*16 + (lane&15)
__global__ void k_wfrag(const float* __restrict__ W, const float* __restrict__ U,
                        unsigned short* __restrict__ wf){
  int flat = blockIdx.x*256 + threadIdx.x;       // 0..196607
  int lane = flat & 63;
  int rest = flat >> 6;                          // 0..3071
  int nt   = rest & 1;
  int kt   = (rest >> 1) % 24;
  int sw   = (rest >> 1) / 24;                   // sub*4 + w
  int w    = sw & 3;
  int sub  = sw >> 2;
  int colg  = w*HS_ + sub*32 + nt*16 + (lane & 15);
  int kbase = kt*32 + (lane >> 4)*8;
  short8 r;
#pragma unroll
  for (int j=0;j<8;j++){
    int k = kbase + j;
    float v = (k < D_) ? W[(size_t)k*2048 + colg] : U[(size_t)(k-D_)*2048 + colg];
    r[j] = (short)f2bf(v);
  }
  *(short8*)(void*)(wf + (size_t)flat*8) = r;
}

// ---- persistent recurrence kernel ----
// grid = 128 WGs x 256 thr. group = wg>>4 owns batch rows [16g,16g+16);
// sub = wg&15 owns h cols [32*sub, 32*sub+32). wave w computes gate chunk w
// (i/f/g/o), 16x32 tile, K=768 via MFMA 16x16x32 bf16 with register-resident B.
// Inter-WG h exchange: ONLY sc1 (device-coherent, L2-bypassing) relaxed
// atomics -- no __threadfence (full L2 wb/inv on gfx950 = 10x slowdown, R1).
__global__ __launch_bounds__(256, 1) void k_lstm(
  const unsigned short* __restrict__ xb,
  const unsigned short* __restrict__ wf,
  const float* __restrict__ bias,
  unsigned short* __restrict__ hbuf,
  unsigned int* __restrict__ cnt,
  float* __restrict__ out)
{
  __shared__ unsigned short A_lds[NKT*64*8];   // 24 KiB, fragment-order
  __shared__ float g_lds[4][16][34];           // gates, padded

  const int wg   = blockIdx.x;
  const int group = wg >> 4, sub = wg & 15;
  const int tid  = threadIdx.x;
  const int wave = tid >> 6, lane = tid & 63;

  // B fragments: 48 x (16B/lane) = 192 VGPRs, resident all 1024 steps
  short8 bw[48];
  {
    const unsigned short* wp = wf + (size_t)(sub*4 + wave)*48*512 + (size_t)lane*8;
#pragma unroll
    for (int i=0;i<48;i++) bw[i] = *(const short8*)(const void*)(wp + i*512);
  }

  // elementwise mapping: row_e = tid>>4, two h-cols per thread
  const int row_e = tid >> 4;
  const int cp    = (tid & 15)*2;
  float bres[8];
#pragma unroll
  for (int q=0;q<4;q++)
#pragma unroll
    for (int e=0;e<2;e++)
      bres[q*2+e] = bias[q*HS_ + sub*32 + cp + e];

  float c0 = 0.f, c1 = 0.f;
  unsigned int* mycnt = cnt + group*64;   // 256B stride
  const size_t HSQ = (size_t)B_*T_*HS_;
  const int grow = group*16 + row_e;
  const int gcol = sub*32 + cp;

  // x staging mapping: id2 = j*256+tid in [0,512): row=id2>>5, kc=id2&31
  const int xrow0 = (tid >> 5);            // j=0 rows 0..7
  const int xkc   = (tid & 31);
  // h staging mapping: id = j*256+tid in [0,2048): row=id>>7, hc=id&127
  // prefetch x for t=0
  short8 xr0, xr1;
  {
    const unsigned short* s0 = xb + ((size_t)(group*16 + xrow0)*T_ + 0)*D_ + xkc*8;
    const unsigned short* s1 = xb + ((size_t)(group*16 + xrow0 + 8)*T_ + 0)*D_ + xkc*8;
    xr0 = *(const short8*)(const void*)s0;
    xr1 = *(const short8*)(const void*)s1;
  }

  for (int t=0; t<T_; ++t){
    // ---- stage A = [x_t | h_t] into LDS in fragment order ----
    {
      int kt = xkc >> 2, quad = xkc & 3;
      *(short8*)(void*)&A_lds[((kt*64) + quad*16 + xrow0    )*8] = xr0;
      *(short8*)(void*)&A_lds[((kt*64) + quad*16 + xrow0 + 8)*8] = xr1;
    }
    const unsigned short* hsrc = hbuf + (size_t)(t & 1)*B_*HS_;
#pragma unroll
    for (int j=0;j<8;j++){
      int id  = j*256 + tid;         // 0..2047
      int row = id >> 7;
      int hc  = id & 127;            // u64 index within row
      unsigned long long v = __hip_atomic_load(
        (const unsigned long long*)(const void*)(hsrc + (size_t)(group*16+row)*HS_ + hc*4),
        __ATOMIC_RELAXED, __HIP_MEMORY_SCOPE_AGENT);
      int kt = 8 + (hc >> 3), quad = (hc >> 1) & 3, off = (hc & 1)*4;
      *(unsigned long long*)(void*)&A_lds[(kt*64 + quad*16 + row)*8 + off] = v;
    }
    __syncthreads();

    // ---- MFMA: gates[16 x 32] for chunk `wave`, K=768 ----
    floatx4 acc0 = {0.f,0.f,0.f,0.f}, acc1 = {0.f,0.f,0.f,0.f};
#pragma unroll
    for (int kt=0; kt<NKT; ++kt){
      short8 a = *(const short8*)(const void*)&A_lds[(kt*64 + lane)*8];
      acc0 = __builtin_amdgcn_mfma_f32_16x16x32_bf16(a, bw[kt*2+0], acc0, 0,0,0);
      acc1 = __builtin_amdgcn_mfma_f32_16x16x32_bf16(a, bw[kt*2+1], acc1, 0,0,0);
    }
    // C/D layout: col = lane&15, row = (lane>>4)*4 + reg
#pragma unroll
    for (int r=0;r<4;r++){
      int row = (lane>>4)*4 + r;
      g_lds[wave][row][(lane&15)]    = acc0[r];
      g_lds[wave][row][16+(lane&15)] = acc1[r];
    }
    __syncthreads();

    // ---- LSTM cell, 2 h/c values per thread (c in registers) ----
    float hv0, hv1;
    {
      float gi = g_lds[0][row_e][cp]   + bres[0];
      float gf = g_lds[1][row_e][cp]   + bres[2];
      float gg = g_lds[2][row_e][cp]   + bres[4];
      float go = g_lds[3][row_e][cp]   + bres[6];
      float i_ = 1.f/(1.f + __expf(-gi));
      float f_ = 1.f/(1.f + __expf(-gf));
      float g_ = 1.f - 2.f/(__expf(2.f*gg)+1.f);
      float o_ = 1.f/(1.f + __expf(-go));
      c0 = f_*c0 + i_*g_;
      hv0 = o_*(1.f - 2.f/(__expf(2.f*c0)+1.f));
    }
    {
      float gi = g_lds[0][row_e][cp+1] + bres[1];
      float gf = g_lds[1][row_e][cp+1] + bres[3];
      float gg = g_lds[2][row_e][cp+1] + bres[5];
      float go = g_lds[3][row_e][cp+1] + bres[7];
      float i_ = 1.f/(1.f + __expf(-gi));
      float f_ = 1.f/(1.f + __expf(-gf));
      float g_ = 1.f - 2.f/(__expf(2.f*gg)+1.f);
      float o_ = 1.f/(1.f + __expf(-go));
      c1 = f_*c1 + i_*g_;
      hv1 = o_*(1.f - 2.f/(__expf(2.f*c1)+1.f));
    }

    // hidden_sequence (fp32, plain store -- not part of inter-WG protocol)
    float2 h2; h2.x = hv0; h2.y = hv1;
    *(float2*)(out + ((size_t)grow*T_ + t)*HS_ + gcol) = h2;
    // next-step h (bf16 packed u32, sc1 device-coherent store)
    unsigned short* hdst = hbuf + (size_t)((t+1)&1)*B_*HS_ + (size_t)grow*HS_ + gcol;
    __hip_atomic_store((unsigned int*)(void*)hdst,
                       (unsigned)f2bf(hv0) | ((unsigned)f2bf(hv1) << 16),
                       __ATOMIC_RELAXED, __HIP_MEMORY_SCOPE_AGENT);
    if (t == T_-1){
      *(float2*)(out + HSQ + (size_t)grow*HS_ + gcol) = h2;
      float2 cc; cc.x = c0; cc.y = c1;
      *(float2*)(out + HSQ + (size_t)B_*HS_ + (size_t)grow*HS_ + gcol) = cc;
    }

    // ---- per-group barrier: monotonic counter, relaxed sc1 atomics only ----
    // __syncthreads drains each wave's vmcnt => all sc1 h-stores visible at
    // the IF$ coherence point before tid0's increment is.
    __syncthreads();
    if (tid == 0){
      __atomic_signal_fence(__ATOMIC_RELEASE);
      __hip_atomic_fetch_add(mycnt, 1u, __ATOMIC_RELAXED, __HIP_MEMORY_SCOPE_AGENT);
    }
    // prefetch next x slice into registers (overlaps the spin)
    if (t+1 < T_){
      const unsigned short* s0 = xb + ((size_t)(group*16 + xrow0)*T_ + (t+1))*D_ + xkc*8;
      const unsigned short* s1 = xb + ((size_t)(group*16 + xrow0 + 8)*T_ + (t+1))*D_ + xkc*8;
      xr0 = *(const short8*)(const void*)s0;
      xr1 = *(const short8*)(const void*)s1;
    }
    if (tid == 0){
      unsigned tgt = 16u*(unsigned)(t+1);
      while (__hip_atomic_load(mycnt, __ATOMIC_RELAXED, __HIP_MEMORY_SCOPE_AGENT) < tgt)
        __builtin_amdgcn_s_sleep(1);
      __atomic_signal_fence(__ATOMIC_ACQUIRE);
    }
    __syncthreads();
  }
}

extern "C" void kernel_launch(void* const* d_in, const int* in_sizes, int n_in,
                              void* d_out, int out_size, void* d_ws, size_t ws_size,
                              hipStream_t stream){
  (void)in_sizes; (void)n_in; (void)out_size; (void)ws_size;
  const float* x    = (const float*)d_in[0];
  const float* W    = (const float*)d_in[1];
  const float* U    = (const float*)d_in[2];
  const float* bias = (const float*)d_in[3];
  char* ws = (char*)d_ws;
  unsigned short* xb = (unsigned short*)(ws + OFF_X);
  unsigned short* wf = (unsigned short*)(ws + OFF_W);
  unsigned short* hb = (unsigned short*)(ws + OFF_H);
  unsigned int*   cn = (unsigned int*)(ws + OFF_C);
  float* out = (float*)d_out;

  hipLaunchKernelGGL(k_zero,  dim3(256),   dim3(256), 0, stream, (unsigned*)hb, cn);
  hipLaunchKernelGGL(k_convx, dim3((B_*T_*D_/8)/256), dim3(256), 0, stream, x, xb);
  hipLaunchKernelGGL(k_wfrag, dim3(768),   dim3(256), 0, stream, W, U, wf);
  hipLaunchKernelGGL(k_lstm,  dim3(128),   dim3(256), 0, stream, xb, wf, bias, hb, cn, out);
}